// Round 1
// baseline (1358.957 us; speedup 1.0000x reference)
//
#include <hip/hip_runtime.h>

#define FEAT 128
#define EMB 64

// ---------------- CSR build ----------------

__global__ void count_deg_kernel(const int* __restrict__ edge_dst, int* __restrict__ deg, int n_edges) {
    int e = blockIdx.x * blockDim.x + threadIdx.x;
    if (e < n_edges) atomicAdd(&deg[edge_dst[e]], 1);
}

// single-block inclusive scan -> rowptr (exclusive, shifted), plus dinv = rsqrt(max(deg,1))
__global__ void scan_kernel(const int* __restrict__ deg, int* __restrict__ rowptr,
                            float* __restrict__ dinv, int n) {
    __shared__ int sdata[1024];
    int tid = threadIdx.x;
    if (tid == 0) rowptr[0] = 0;
    int carry = 0;
    int nchunks = (n + 1023) / 1024;
    for (int c = 0; c < nchunks; ++c) {
        int i = c * 1024 + tid;
        int v = (i < n) ? deg[i] : 0;
        if (i < n) dinv[i] = rsqrtf(fmaxf((float)v, 1.0f));
        sdata[tid] = v;
        __syncthreads();
        for (int off = 1; off < 1024; off <<= 1) {
            int t = (tid >= off) ? sdata[tid - off] : 0;
            __syncthreads();
            sdata[tid] += t;
            __syncthreads();
        }
        if (i < n) rowptr[i + 1] = carry + sdata[tid];
        carry += sdata[1023];
        __syncthreads();
    }
}

__global__ void fill_csr_kernel(const int* __restrict__ edge_src, const int* __restrict__ edge_dst,
                                const int* __restrict__ rowptr, int* __restrict__ cursor,
                                int* __restrict__ csr_src, int n_edges) {
    int e = blockIdx.x * blockDim.x + threadIdx.x;
    if (e < n_edges) {
        int d = edge_dst[e];
        int pos = rowptr[d] + atomicAdd(&cursor[d], 1);
        csr_src[pos] = edge_src[e];
    }
}

// ---------------- MLP: h = relu(relu(feat@W1+b1)@W2+b2) ----------------

__global__ __launch_bounds__(256) void mlp_kernel(const float* __restrict__ feat,
        const float* __restrict__ W1, const float* __restrict__ b1,
        const float* __restrict__ W2, const float* __restrict__ b2,
        float* __restrict__ h, int n) {
    __shared__ float sW1[FEAT * EMB];   // 32 KB
    __shared__ float sW2[EMB * EMB];    // 16 KB
    __shared__ float sb1[EMB], sb2[EMB];
    int tid = threadIdx.x;
    for (int i = tid; i < FEAT * EMB; i += 256) sW1[i] = W1[i];
    for (int i = tid; i < EMB * EMB; i += 256) sW2[i] = W2[i];
    if (tid < EMB) { sb1[tid] = b1[tid]; sb2[tid] = b2[tid]; }
    __syncthreads();
    int lane = tid & 63;
    int wave = (blockIdx.x * blockDim.x + tid) >> 6;
    int nwaves = (gridDim.x * blockDim.x) >> 6;
    for (int r = wave; r < n; r += nwaves) {
        float f0 = feat[r * FEAT + lane];
        float f1 = feat[r * FEAT + 64 + lane];
        float acc = sb1[lane];
        #pragma unroll 16
        for (int k = 0; k < 64; ++k) {
            float fk = __shfl(f0, k);
            acc += fk * sW1[k * EMB + lane];
        }
        #pragma unroll 16
        for (int k = 0; k < 64; ++k) {
            float fk = __shfl(f1, k);
            acc += fk * sW1[(64 + k) * EMB + lane];
        }
        float h0 = fmaxf(acc, 0.0f);
        float acc2 = sb2[lane];
        #pragma unroll 16
        for (int m = 0; m < 64; ++m) {
            float hm = __shfl(h0, m);
            acc2 += hm * sW2[m * EMB + lane];
        }
        h[r * EMB + lane] = fmaxf(acc2, 0.0f);
    }
}

// ---------------- Laplacian gather kernels ----------------
// lap(x)[i] = x[i] - dinv[i] * sum_{e: dst=i} x[src]*dinv[src]

__global__ __launch_bounds__(256) void lap_kernel(const float* __restrict__ x, float* __restrict__ out,
        const int* __restrict__ rowptr, const int* __restrict__ csr_src,
        const float* __restrict__ dinv, int n) {
    int tid = blockIdx.x * blockDim.x + threadIdx.x;
    int i = tid >> 6;
    int lane = tid & 63;
    if (i >= n) return;
    int s = rowptr[i], e = rowptr[i + 1];
    float acc = 0.0f;
    for (int p = s; p < e; ++p) {
        int src = csr_src[p];
        acc += x[src * EMB + lane] * dinv[src];
    }
    out[i * EMB + lane] = x[i * EMB + lane] - acc * dinv[i];
}

// A = t0*A + t1*B + t2*lap(B)   (in-place on A: each thread touches only its own row)
__global__ __launch_bounds__(256) void theta_kernel(float* __restrict__ A, const float* __restrict__ B,
        const int* __restrict__ rowptr, const int* __restrict__ csr_src,
        const float* __restrict__ dinv, int n, float t0, float t1, float t2) {
    int tid = blockIdx.x * blockDim.x + threadIdx.x;
    int i = tid >> 6;
    int lane = tid & 63;
    if (i >= n) return;
    int s = rowptr[i], e = rowptr[i + 1];
    float acc = 0.0f;
    for (int p = s; p < e; ++p) {
        int src = csr_src[p];
        acc += B[src * EMB + lane] * dinv[src];
    }
    int idx = i * EMB + lane;
    float lapB = B[idx] - acc * dinv[i];
    A[idx] = t0 * A[idx] + t1 * B[idx] + t2 * lapB;
}

// ---------------- Final: vtmp = feat[node] + (h[node]@W3 + b3); scores ----------------

__global__ __launch_bounds__(256) void final1_kernel(const float* __restrict__ feat,
        const float* __restrict__ h, const float* __restrict__ W3, const float* __restrict__ b3,
        const float* __restrict__ Wclf, const float* __restrict__ bclf,
        const int* __restrict__ nodes, float* __restrict__ vtmp, float* __restrict__ scores,
        int n) {
    __shared__ float sW3[EMB * FEAT];  // 32 KB
    __shared__ float sWclf[FEAT * 2];
    __shared__ float sb3[FEAT];
    int tid = threadIdx.x;
    for (int i = tid; i < EMB * FEAT; i += 256) sW3[i] = W3[i];
    for (int i = tid; i < FEAT * 2; i += 256) sWclf[i] = Wclf[i];
    if (tid < FEAT) sb3[tid] = b3[tid];
    __syncthreads();
    float bc0 = bclf[0], bc1 = bclf[1];
    int lane = tid & 63;
    int wave = (blockIdx.x * blockDim.x + tid) >> 6;
    int nwaves = (gridDim.x * blockDim.x) >> 6;
    for (int i = wave; i < n; i += nwaves) {
        int node = nodes[i];
        float hl = h[node * EMB + lane];
        float f0 = feat[node * FEAT + lane];
        float f1 = feat[node * FEAT + 64 + lane];
        float spe0 = sb3[lane], spe1 = sb3[64 + lane];
        #pragma unroll 16
        for (int m = 0; m < 64; ++m) {
            float hm = __shfl(hl, m);
            spe0 += hm * sW3[m * FEAT + lane];
            spe1 += hm * sW3[m * FEAT + 64 + lane];
        }
        vtmp[i * FEAT + lane] = f0 + spe0;
        vtmp[i * FEAT + 64 + lane] = f1 + spe1;
        // center scores: wave-reduce partial dot products
        float p0 = f0 * sWclf[lane * 2 + 0] + f1 * sWclf[(64 + lane) * 2 + 0];
        float p1 = f0 * sWclf[lane * 2 + 1] + f1 * sWclf[(64 + lane) * 2 + 1];
        for (int off = 32; off > 0; off >>= 1) {
            p0 += __shfl_xor(p0, off);
            p1 += __shfl_xor(p1, off);
        }
        if (lane == 0) {
            scores[i * 2 + 0] = p0 + bc0;
            scores[i * 2 + 1] = p1 + bc1;
        }
    }
}

// combined = relu(vtmp @ weight)
__global__ __launch_bounds__(256) void final2_kernel(const float* __restrict__ vtmp,
        const float* __restrict__ weight, float* __restrict__ outc, int n) {
    __shared__ float sW[FEAT * EMB];  // 32 KB
    int tid = threadIdx.x;
    for (int i = tid; i < FEAT * EMB; i += 256) sW[i] = weight[i];
    __syncthreads();
    int lane = tid & 63;
    int wave = (blockIdx.x * blockDim.x + tid) >> 6;
    int nwaves = (gridDim.x * blockDim.x) >> 6;
    for (int i = wave; i < n; i += nwaves) {
        float v0 = vtmp[i * FEAT + lane];
        float v1 = vtmp[i * FEAT + 64 + lane];
        float acc = 0.0f;
        #pragma unroll 16
        for (int k = 0; k < 64; ++k) {
            float vk = __shfl(v0, k);
            acc += vk * sW[k * EMB + lane];
        }
        #pragma unroll 16
        for (int k = 0; k < 64; ++k) {
            float vk = __shfl(v1, k);
            acc += vk * sW[(64 + k) * EMB + lane];
        }
        outc[i * EMB + lane] = fmaxf(acc, 0.0f);
    }
}

// ---------------- launch ----------------

extern "C" void kernel_launch(void* const* d_in, const int* in_sizes, int n_in,
                              void* d_out, int out_size, void* d_ws, size_t ws_size,
                              hipStream_t stream) {
    const float* feat   = (const float*)d_in[0];
    const float* Wclf   = (const float*)d_in[1];
    const float* bclf   = (const float*)d_in[2];
    const float* W1     = (const float*)d_in[3];
    const float* b1     = (const float*)d_in[4];
    const float* W2     = (const float*)d_in[5];
    const float* b2     = (const float*)d_in[6];
    const float* W3     = (const float*)d_in[7];
    const float* b3     = (const float*)d_in[8];
    const float* weight = (const float*)d_in[9];
    const int* nodes    = (const int*)d_in[10];
    // d_in[11] = r1_neighs: DEAD (AGG_WEIGHT[0] == 0.0 multiplies that branch away)
    const int* edge_src = (const int*)d_in[12];
    const int* edge_dst = (const int*)d_in[13];

    int n       = in_sizes[10];        // 8192
    int n_edges = in_sizes[12];        // 1600000
    int N       = in_sizes[0] / FEAT;  // 50000

    char* ws = (char*)d_ws;
    size_t off = 0;
    auto alloc = [&](size_t bytes) -> void* {
        void* p = ws + off;
        off = (off + bytes + 255) & ~(size_t)255;
        return p;
    };
    int*   deg    = (int*)  alloc((size_t)N * 4);
    int*   cursor = (int*)  alloc((size_t)N * 4);
    int*   rowptr = (int*)  alloc((size_t)(N + 1) * 4);
    float* dinv   = (float*)alloc((size_t)N * 4);
    int*   csr    = (int*)  alloc((size_t)n_edges * 4);
    float* A      = (float*)alloc((size_t)N * EMB * 4);
    float* B      = (float*)alloc((size_t)N * EMB * 4);
    float* vtmp   = (float*)alloc((size_t)n * FEAT * 4);

    float* out_combined = (float*)d_out;                       // [n, 64]
    float* out_scores   = out_combined + (size_t)n * EMB;      // [n, 2]

    hipMemsetAsync(deg, 0, (size_t)N * 4, stream);
    hipMemsetAsync(cursor, 0, (size_t)N * 4, stream);

    int eb = (n_edges + 255) / 256;
    count_deg_kernel<<<eb, 256, 0, stream>>>(edge_dst, deg, n_edges);
    scan_kernel<<<1, 1024, 0, stream>>>(deg, rowptr, dinv, N);
    fill_csr_kernel<<<eb, 256, 0, stream>>>(edge_src, edge_dst, rowptr, cursor, csr, n_edges);

    mlp_kernel<<<512, 256, 0, stream>>>(feat, W1, b1, W2, b2, A, N);

    int nb = (N * 64 + 255) / 256;  // one wave per node
    const float th[3][3] = {{3.f, -3.f, 0.75f}, {0.f, 3.f, -1.5f}, {0.f, 0.f, 0.75f}};
    for (int t = 0; t < 3; ++t) {
        lap_kernel<<<nb, 256, 0, stream>>>(A, B, rowptr, csr, dinv, N);
        theta_kernel<<<nb, 256, 0, stream>>>(A, B, rowptr, csr, dinv, N,
                                             th[t][0], th[t][1], th[t][2]);
    }

    final1_kernel<<<256, 256, 0, stream>>>(feat, A, W3, b3, Wclf, bclf, nodes,
                                           vtmp, out_scores, n);
    final2_kernel<<<256, 256, 0, stream>>>(vtmp, weight, out_combined, n);
}

// Round 3
// 742.606 us; speedup vs baseline: 1.8300x; 1.8300x over previous
//
#include <hip/hip_runtime.h>

#define FEAT 128
#define EMB 64

// ============ CSR build ============

__global__ void count_deg_kernel(const int* __restrict__ edge_dst, int* __restrict__ deg, int n_edges) {
    int e = blockIdx.x * blockDim.x + threadIdx.x;
    if (e < n_edges) atomicAdd(&deg[edge_dst[e]], 1);
}

__global__ void block_sum_kernel(const int* __restrict__ deg, int* __restrict__ bsum, int n) {
    __shared__ int sd[256];
    int t = threadIdx.x;
    int i = blockIdx.x * 256 + t;
    sd[t] = (i < n) ? deg[i] : 0;
    __syncthreads();
    for (int off = 128; off > 0; off >>= 1) {
        if (t < off) sd[t] += sd[t + off];
        __syncthreads();
    }
    if (t == 0) bsum[blockIdx.x] = sd[0];
}

__global__ void scan_bsum_kernel(const int* __restrict__ bsum, int* __restrict__ boff, int nb) {
    __shared__ int sd[256];
    int t = threadIdx.x;
    int v = (t < nb) ? bsum[t] : 0;
    sd[t] = v;
    __syncthreads();
    for (int off = 1; off < 256; off <<= 1) {
        int u = (t >= off) ? sd[t - off] : 0;
        __syncthreads();
        sd[t] += u;
        __syncthreads();
    }
    if (t < nb) boff[t] = sd[t] - v;   // exclusive offsets
}

__global__ void scan_fill_kernel(const int* __restrict__ deg, const int* __restrict__ boff,
                                 int* __restrict__ rowptr, float* __restrict__ dinv, int n) {
    __shared__ int sd[256];
    int t = threadIdx.x;
    int i = blockIdx.x * 256 + t;
    int v = (i < n) ? deg[i] : 0;
    sd[t] = v;
    __syncthreads();
    for (int off = 1; off < 256; off <<= 1) {
        int u = (t >= off) ? sd[t - off] : 0;
        __syncthreads();
        sd[t] += u;
        __syncthreads();
    }
    if (i < n) {
        rowptr[i + 1] = boff[blockIdx.x] + sd[t];
        dinv[i] = rsqrtf(fmaxf((float)v, 1.0f));
    }
    if (i == 0) rowptr[0] = 0;
}

__global__ void fill_csr_kernel(const int* __restrict__ edge_src, const int* __restrict__ edge_dst,
                                const int* __restrict__ rowptr, int* __restrict__ cursor,
                                int* __restrict__ csr_src, int n_edges) {
    int e = blockIdx.x * blockDim.x + threadIdx.x;
    if (e < n_edges) {
        int d = edge_dst[e];
        int pos = rowptr[d] + atomicAdd(&cursor[d], 1);
        csr_src[pos] = edge_src[e];
    }
}

// ============ MLP: A = relu(relu(feat@W1+b1)@W2+b2); Ay = A*dinv ============
// 64 rows/block, 256 threads, 4x4 register tile, float4 LDS reads. LDS = exactly 64KB.

__global__ __launch_bounds__(256) void mlp_kernel(const float* __restrict__ feat,
        const float* __restrict__ W1, const float* __restrict__ b1,
        const float* __restrict__ W2, const float* __restrict__ b2,
        const float* __restrict__ dinv,
        float* __restrict__ A, float* __restrict__ Ay, int n) {
    __shared__ float sW1[FEAT * EMB];   // 32KB
    __shared__ float sBuf[64 * FEAT];   // 32KB: feat tile; later sH[64*64] + sW2[64*64]
    int tid = threadIdx.x;
    int row0 = blockIdx.x * 64;

    for (int i = tid; i < FEAT * EMB; i += 256) sW1[i] = W1[i];
    for (int i = tid; i < 64 * FEAT; i += 256) {
        int r = i >> 7, c = i & 127;
        int gr = row0 + r;
        sBuf[i] = (gr < n) ? feat[(size_t)gr * FEAT + c] : 0.0f;
    }
    __syncthreads();

    int tx = tid & 15, ty = tid >> 4;   // 16 col-groups x 16 row-groups
    float4 b1v = *(const float4*)&b1[tx * 4];
    float acc[4][4];
    #pragma unroll
    for (int i = 0; i < 4; ++i) { acc[i][0]=b1v.x; acc[i][1]=b1v.y; acc[i][2]=b1v.z; acc[i][3]=b1v.w; }

    #pragma unroll 4
    for (int k4 = 0; k4 < FEAT / 4; ++k4) {
        float4 a4[4];
        #pragma unroll
        for (int i = 0; i < 4; ++i)
            a4[i] = *(const float4*)&sBuf[(ty * 4 + i) * FEAT + k4 * 4];
        #pragma unroll
        for (int kk = 0; kk < 4; ++kk) {
            float4 bv = *(const float4*)&sW1[(k4 * 4 + kk) * EMB + tx * 4];
            #pragma unroll
            for (int i = 0; i < 4; ++i) {
                float a = ((const float*)&a4[i])[kk];
                acc[i][0] = fmaf(a, bv.x, acc[i][0]);
                acc[i][1] = fmaf(a, bv.y, acc[i][1]);
                acc[i][2] = fmaf(a, bv.z, acc[i][2]);
                acc[i][3] = fmaf(a, bv.w, acc[i][3]);
            }
        }
    }
    __syncthreads();

    // reuse sBuf: sH = [0..4096), sW2 = [4096..8192)
    float* sH = sBuf;
    float* sW2p = sBuf + 64 * EMB;
    #pragma unroll
    for (int i = 0; i < 4; ++i)
        #pragma unroll
        for (int j = 0; j < 4; ++j)
            sH[(ty * 4 + i) * EMB + tx * 4 + j] = fmaxf(acc[i][j], 0.0f);
    for (int i = tid; i < EMB * EMB; i += 256) sW2p[i] = W2[i];
    __syncthreads();

    float4 b2v = *(const float4*)&b2[tx * 4];
    float acc2[4][4];
    #pragma unroll
    for (int i = 0; i < 4; ++i) { acc2[i][0]=b2v.x; acc2[i][1]=b2v.y; acc2[i][2]=b2v.z; acc2[i][3]=b2v.w; }

    #pragma unroll 4
    for (int k4 = 0; k4 < EMB / 4; ++k4) {
        float4 a4[4];
        #pragma unroll
        for (int i = 0; i < 4; ++i)
            a4[i] = *(const float4*)&sH[(ty * 4 + i) * EMB + k4 * 4];
        #pragma unroll
        for (int kk = 0; kk < 4; ++kk) {
            float4 bv = *(const float4*)&sW2p[(k4 * 4 + kk) * EMB + tx * 4];
            #pragma unroll
            for (int i = 0; i < 4; ++i) {
                float a = ((const float*)&a4[i])[kk];
                acc2[i][0] = fmaf(a, bv.x, acc2[i][0]);
                acc2[i][1] = fmaf(a, bv.y, acc2[i][1]);
                acc2[i][2] = fmaf(a, bv.z, acc2[i][2]);
                acc2[i][3] = fmaf(a, bv.w, acc2[i][3]);
            }
        }
    }

    #pragma unroll
    for (int i = 0; i < 4; ++i) {
        int gr = row0 + ty * 4 + i;
        if (gr < n) {
            float di = dinv[gr];
            float4 o;
            o.x = fmaxf(acc2[i][0], 0.0f); o.y = fmaxf(acc2[i][1], 0.0f);
            o.z = fmaxf(acc2[i][2], 0.0f); o.w = fmaxf(acc2[i][3], 0.0f);
            *(float4*)&A[(size_t)gr * EMB + tx * 4] = o;
            float4 oy; oy.x = o.x * di; oy.y = o.y * di; oy.z = o.z * di; oy.w = o.w * di;
            *(float4*)&Ay[(size_t)gr * EMB + tx * 4] = oy;
        }
    }
}

// ============ Laplacian kernels ============
// y = x*dinv precomputed. lap(x)[i] = x[i] - dinv[i]*sum_{src->i} y[src]
// 16 lanes per node, float4 per lane.

__global__ __launch_bounds__(256) void lap_kernel(
        const float4* __restrict__ x, const float4* __restrict__ y,
        float4* __restrict__ Bx, float4* __restrict__ By,
        const int* __restrict__ rowptr, const int* __restrict__ csr,
        const float* __restrict__ dinv, int n) {
    int tid = blockIdx.x * blockDim.x + threadIdx.x;
    int g = tid >> 4, gl = tid & 15;
    if (g >= n) return;
    int s = rowptr[g], e = rowptr[g + 1];
    float4 acc = {0.f, 0.f, 0.f, 0.f};
    for (int p = s; p < e; ++p) {
        int src = csr[p];
        float4 v = y[(size_t)src * 16 + gl];
        acc.x += v.x; acc.y += v.y; acc.z += v.z; acc.w += v.w;
    }
    float di = dinv[g];
    float4 xv = x[(size_t)g * 16 + gl];
    float4 o;
    o.x = xv.x - acc.x * di; o.y = xv.y - acc.y * di;
    o.z = xv.z - acc.z * di; o.w = xv.w - acc.w * di;
    Bx[(size_t)g * 16 + gl] = o;
    float4 oy; oy.x = o.x * di; oy.y = o.y * di; oy.z = o.z * di; oy.w = o.w * di;
    By[(size_t)g * 16 + gl] = oy;
}

// A = t0*A + t1*B + t2*(B - dinv*sum By[src]); Ay = A*dinv
__global__ __launch_bounds__(256) void theta_kernel(
        float4* __restrict__ Ax, float4* __restrict__ Ay,
        const float4* __restrict__ Bx, const float4* __restrict__ By,
        const int* __restrict__ rowptr, const int* __restrict__ csr,
        const float* __restrict__ dinv, int n, float t0, float t1, float t2) {
    int tid = blockIdx.x * blockDim.x + threadIdx.x;
    int g = tid >> 4, gl = tid & 15;
    if (g >= n) return;
    int s = rowptr[g], e = rowptr[g + 1];
    float4 acc = {0.f, 0.f, 0.f, 0.f};
    for (int p = s; p < e; ++p) {
        int src = csr[p];
        float4 v = By[(size_t)src * 16 + gl];
        acc.x += v.x; acc.y += v.y; acc.z += v.z; acc.w += v.w;
    }
    float di = dinv[g];
    float4 bv = Bx[(size_t)g * 16 + gl];
    float4 av = Ax[(size_t)g * 16 + gl];
    float4 lapB;
    lapB.x = bv.x - acc.x * di; lapB.y = bv.y - acc.y * di;
    lapB.z = bv.z - acc.z * di; lapB.w = bv.w - acc.w * di;
    float4 o;
    o.x = t0 * av.x + t1 * bv.x + t2 * lapB.x;
    o.y = t0 * av.y + t1 * bv.y + t2 * lapB.y;
    o.z = t0 * av.z + t1 * bv.z + t2 * lapB.z;
    o.w = t0 * av.w + t1 * bv.w + t2 * lapB.w;
    Ax[(size_t)g * 16 + gl] = o;
    float4 oy; oy.x = o.x * di; oy.y = o.y * di; oy.z = o.z * di; oy.w = o.w * di;
    Ay[(size_t)g * 16 + gl] = oy;
}

// ============ Final stage 1: vtmp = feat[node] + h[node]@W3 + b3 ; scores ============
// 64 nodes/block, 256 threads, 8x4 register tile over 64x128 output, K=64.

__global__ __launch_bounds__(256) void final1_kernel(const float* __restrict__ feat,
        const float* __restrict__ h, const float* __restrict__ W3, const float* __restrict__ b3,
        const float* __restrict__ Wclf, const float* __restrict__ bclf,
        const int* __restrict__ nodes, float* __restrict__ vtmp, float* __restrict__ scores,
        int n) {
    __shared__ float sW3[EMB * FEAT];    // 32KB, [64][128]
    __shared__ float sHt[64 * 68];       // 17KB padded
    __shared__ float sWclf[FEAT * 2];
    __shared__ float sb3[FEAT];
    __shared__ float sbclf[2];
    __shared__ int sNodes[64];
    int tid = threadIdx.x;
    int base = blockIdx.x * 64;

    for (int i = tid; i < EMB * FEAT; i += 256) sW3[i] = W3[i];
    for (int i = tid; i < FEAT * 2; i += 256) sWclf[i] = Wclf[i];
    if (tid < FEAT) sb3[tid] = b3[tid];
    if (tid < 2) sbclf[tid] = bclf[tid];
    if (tid < 64) {
        int gi = base + tid;
        sNodes[tid] = (gi < n) ? nodes[gi] : 0;
    }
    __syncthreads();
    // gather h rows: 64 consecutive threads load one row
    for (int it = 0; it < 16; ++it) {
        int id = it * 256 + tid;
        int r = id >> 6, c = id & 63;
        sHt[r * 68 + c] = h[(size_t)sNodes[r] * EMB + c];
    }
    __syncthreads();

    // scores: wave w handles nodes w*16..w*16+15
    {
        int wv = tid >> 6, ln = tid & 63;
        float bc0 = sbclf[0], bc1 = sbclf[1];
        for (int q = 0; q < 16; ++q) {
            int r = wv * 16 + q;
            int nd = sNodes[r];
            float f0 = feat[(size_t)nd * FEAT + ln];
            float f1 = feat[(size_t)nd * FEAT + 64 + ln];
            float p0 = f0 * sWclf[ln * 2]     + f1 * sWclf[(64 + ln) * 2];
            float p1 = f0 * sWclf[ln * 2 + 1] + f1 * sWclf[(64 + ln) * 2 + 1];
            #pragma unroll
            for (int off = 32; off > 0; off >>= 1) {
                p0 += __shfl_xor(p0, off);
                p1 += __shfl_xor(p1, off);
            }
            int gi = base + r;
            if (ln == 0 && gi < n) {
                scores[(size_t)gi * 2]     = p0 + bc0;
                scores[(size_t)gi * 2 + 1] = p1 + bc1;
            }
        }
    }

    int tx = tid & 31, ty = tid >> 5;    // 32 col-groups x 8 row-groups (8 rows each)
    float acc[8][4];
    #pragma unroll
    for (int i = 0; i < 8; ++i)
        #pragma unroll
        for (int j = 0; j < 4; ++j) acc[i][j] = 0.0f;

    #pragma unroll 2
    for (int k4 = 0; k4 < EMB / 4; ++k4) {
        float4 a4[8];
        #pragma unroll
        for (int i = 0; i < 8; ++i)
            a4[i] = *(const float4*)&sHt[(ty * 8 + i) * 68 + k4 * 4];
        #pragma unroll
        for (int kk = 0; kk < 4; ++kk) {
            float4 bv = *(const float4*)&sW3[(k4 * 4 + kk) * FEAT + tx * 4];
            #pragma unroll
            for (int i = 0; i < 8; ++i) {
                float a = ((const float*)&a4[i])[kk];
                acc[i][0] = fmaf(a, bv.x, acc[i][0]);
                acc[i][1] = fmaf(a, bv.y, acc[i][1]);
                acc[i][2] = fmaf(a, bv.z, acc[i][2]);
                acc[i][3] = fmaf(a, bv.w, acc[i][3]);
            }
        }
    }

    float4 b3v = *(const float4*)&sb3[tx * 4];
    #pragma unroll
    for (int i = 0; i < 8; ++i) {
        int r = ty * 8 + i;
        int gi = base + r;
        int nd = sNodes[r];
        float4 fv = *(const float4*)&feat[(size_t)nd * FEAT + tx * 4];
        float4 o;
        o.x = acc[i][0] + b3v.x + fv.x;
        o.y = acc[i][1] + b3v.y + fv.y;
        o.z = acc[i][2] + b3v.z + fv.z;
        o.w = acc[i][3] + b3v.w + fv.w;
        if (gi < n) *(float4*)&vtmp[(size_t)gi * FEAT + tx * 4] = o;
    }
}

// ============ Final stage 2: out = relu(vtmp @ weight) ============
// 64 rows/block, 4x4 tile, K=128. LDS exactly 64KB.

__global__ __launch_bounds__(256) void final2_kernel(const float* __restrict__ vtmp,
        const float* __restrict__ weight, float* __restrict__ outc, int n) {
    __shared__ float sWt[FEAT * EMB];   // 32KB
    __shared__ float sV[64 * FEAT];     // 32KB
    int tid = threadIdx.x;
    int base = blockIdx.x * 64;
    for (int i = tid; i < FEAT * EMB; i += 256) sWt[i] = weight[i];
    for (int i = tid; i < 64 * FEAT; i += 256) {
        int r = i >> 7, c = i & 127;
        int gi = base + r;
        sV[i] = (gi < n) ? vtmp[(size_t)gi * FEAT + c] : 0.0f;
    }
    __syncthreads();

    int tx = tid & 15, ty = tid >> 4;
    float acc[4][4];
    #pragma unroll
    for (int i = 0; i < 4; ++i)
        #pragma unroll
        for (int j = 0; j < 4; ++j) acc[i][j] = 0.0f;

    #pragma unroll 4
    for (int k4 = 0; k4 < FEAT / 4; ++k4) {
        float4 a4[4];
        #pragma unroll
        for (int i = 0; i < 4; ++i)
            a4[i] = *(const float4*)&sV[(ty * 4 + i) * FEAT + k4 * 4];
        #pragma unroll
        for (int kk = 0; kk < 4; ++kk) {
            float4 bv = *(const float4*)&sWt[(k4 * 4 + kk) * EMB + tx * 4];
            #pragma unroll
            for (int i = 0; i < 4; ++i) {
                float a = ((const float*)&a4[i])[kk];
                acc[i][0] = fmaf(a, bv.x, acc[i][0]);
                acc[i][1] = fmaf(a, bv.y, acc[i][1]);
                acc[i][2] = fmaf(a, bv.z, acc[i][2]);
                acc[i][3] = fmaf(a, bv.w, acc[i][3]);
            }
        }
    }

    #pragma unroll
    for (int i = 0; i < 4; ++i) {
        int gi = base + ty * 4 + i;
        if (gi < n) {
            float4 o;
            o.x = fmaxf(acc[i][0], 0.0f); o.y = fmaxf(acc[i][1], 0.0f);
            o.z = fmaxf(acc[i][2], 0.0f); o.w = fmaxf(acc[i][3], 0.0f);
            *(float4*)&outc[(size_t)gi * EMB + tx * 4] = o;
        }
    }
}

// ============ launch ============

extern "C" void kernel_launch(void* const* d_in, const int* in_sizes, int n_in,
                              void* d_out, int out_size, void* d_ws, size_t ws_size,
                              hipStream_t stream) {
    const float* feat   = (const float*)d_in[0];
    const float* Wclf   = (const float*)d_in[1];
    const float* bclf   = (const float*)d_in[2];
    const float* W1     = (const float*)d_in[3];
    const float* b1     = (const float*)d_in[4];
    const float* W2     = (const float*)d_in[5];
    const float* b2     = (const float*)d_in[6];
    const float* W3     = (const float*)d_in[7];
    const float* b3     = (const float*)d_in[8];
    const float* weight = (const float*)d_in[9];
    const int* nodes    = (const int*)d_in[10];
    // d_in[11] = r1_neighs: DEAD (AGG_WEIGHT[0] == 0.0)
    const int* edge_src = (const int*)d_in[12];
    const int* edge_dst = (const int*)d_in[13];

    int n       = in_sizes[10];        // 8192
    int n_edges = in_sizes[12];        // 1600000
    int N       = in_sizes[0] / FEAT;  // 50000

    char* ws = (char*)d_ws;
    size_t off = 0;
    auto alloc = [&](size_t bytes) -> void* {
        void* p = ws + off;
        off = (off + bytes + 255) & ~(size_t)255;
        return p;
    };
    int*   deg    = (int*)  alloc((size_t)N * 4);
    int*   cursor = (int*)  alloc((size_t)N * 4);
    int*   rowptr = (int*)  alloc((size_t)(N + 1) * 4);
    float* dinv   = (float*)alloc((size_t)N * 4);
    int*   bsum   = (int*)  alloc(256 * 4);
    int*   boff   = (int*)  alloc(256 * 4);
    int*   csr    = (int*)  alloc((size_t)n_edges * 4);
    float* Axf    = (float*)alloc((size_t)N * EMB * 4);
    float* Ayf    = (float*)alloc((size_t)N * EMB * 4);
    float* Bxf    = (float*)alloc((size_t)N * EMB * 4);
    float* Byf    = (float*)alloc((size_t)N * EMB * 4);
    float* vtmp   = (float*)alloc((size_t)n * FEAT * 4);

    float* out_combined = (float*)d_out;                       // [n, 64]
    float* out_scores   = out_combined + (size_t)n * EMB;      // [n, 2]

    hipMemsetAsync(deg, 0, (size_t)N * 4, stream);
    hipMemsetAsync(cursor, 0, (size_t)N * 4, stream);

    int eb = (n_edges + 255) / 256;
    int sb = (N + 255) / 256;   // 196
    count_deg_kernel<<<eb, 256, 0, stream>>>(edge_dst, deg, n_edges);
    block_sum_kernel<<<sb, 256, 0, stream>>>(deg, bsum, N);
    scan_bsum_kernel<<<1, 256, 0, stream>>>(bsum, boff, sb);
    scan_fill_kernel<<<sb, 256, 0, stream>>>(deg, boff, rowptr, dinv, N);
    fill_csr_kernel<<<eb, 256, 0, stream>>>(edge_src, edge_dst, rowptr, cursor, csr, n_edges);

    int mb = (N + 63) / 64;     // 782
    mlp_kernel<<<mb, 256, 0, stream>>>(feat, W1, b1, W2, b2, dinv, Axf, Ayf, N);

    int lb = ((size_t)N * 16 + 255) / 256;  // 3125
    const float th[3][3] = {{3.f, -3.f, 0.75f}, {0.f, 3.f, -1.5f}, {0.f, 0.f, 0.75f}};
    for (int t = 0; t < 3; ++t) {
        lap_kernel<<<lb, 256, 0, stream>>>((const float4*)Axf, (const float4*)Ayf,
                                           (float4*)Bxf, (float4*)Byf,
                                           rowptr, csr, dinv, N);
        theta_kernel<<<lb, 256, 0, stream>>>((float4*)Axf, (float4*)Ayf,
                                             (const float4*)Bxf, (const float4*)Byf,
                                             rowptr, csr, dinv, N,
                                             th[t][0], th[t][1], th[t][2]);
    }

    int fb = (n + 63) / 64;     // 128
    final1_kernel<<<fb, 256, 0, stream>>>(feat, Axf, W3, b3, Wclf, bclf, nodes,
                                          vtmp, out_scores, n);
    final2_kernel<<<fb, 256, 0, stream>>>(vtmp, weight, out_combined, n);
}

// Round 4
// 690.091 us; speedup vs baseline: 1.9692x; 1.0761x over previous
//
#include <hip/hip_runtime.h>

#define FEAT 128
#define EMB 64

typedef unsigned short u16;

__device__ inline u16 f2bf(float f) {
    unsigned u = __float_as_uint(f);
    unsigned r = (u + 0x7FFFu + ((u >> 16) & 1u)) >> 16;
    return (u16)r;
}
__device__ inline float bf2f(u16 h) {
    return __uint_as_float(((unsigned)h) << 16);
}

// ============ CSR build ============

__global__ void count_deg_kernel(const int* __restrict__ edge_dst, int* __restrict__ deg, int n_edges) {
    int e = blockIdx.x * blockDim.x + threadIdx.x;
    if (e < n_edges) atomicAdd(&deg[edge_dst[e]], 1);
}

__global__ void block_sum_kernel(const int* __restrict__ deg, int* __restrict__ bsum, int n) {
    __shared__ int sd[256];
    int t = threadIdx.x;
    int i = blockIdx.x * 256 + t;
    sd[t] = (i < n) ? deg[i] : 0;
    __syncthreads();
    for (int off = 128; off > 0; off >>= 1) {
        if (t < off) sd[t] += sd[t + off];
        __syncthreads();
    }
    if (t == 0) bsum[blockIdx.x] = sd[0];
}

__global__ void scan_bsum_kernel(const int* __restrict__ bsum, int* __restrict__ boff, int nb) {
    __shared__ int sd[256];
    int t = threadIdx.x;
    int v = (t < nb) ? bsum[t] : 0;
    sd[t] = v;
    __syncthreads();
    for (int off = 1; off < 256; off <<= 1) {
        int u = (t >= off) ? sd[t - off] : 0;
        __syncthreads();
        sd[t] += u;
        __syncthreads();
    }
    if (t < nb) boff[t] = sd[t] - v;   // exclusive offsets
}

__global__ void scan_fill_kernel(const int* __restrict__ deg, const int* __restrict__ boff,
                                 int* __restrict__ rowptr, float* __restrict__ dinv, int n) {
    __shared__ int sd[256];
    int t = threadIdx.x;
    int i = blockIdx.x * 256 + t;
    int v = (i < n) ? deg[i] : 0;
    sd[t] = v;
    __syncthreads();
    for (int off = 1; off < 256; off <<= 1) {
        int u = (t >= off) ? sd[t - off] : 0;
        __syncthreads();
        sd[t] += u;
        __syncthreads();
    }
    if (i < n) {
        rowptr[i + 1] = boff[blockIdx.x] + sd[t];
        dinv[i] = rsqrtf(fmaxf((float)v, 1.0f));
    }
    if (i == 0) rowptr[0] = 0;
}

// cursor pre-initialized to rowptr via d2d copy
__global__ void fill_csr_kernel(const int* __restrict__ edge_src, const int* __restrict__ edge_dst,
                                int* __restrict__ cursor, int* __restrict__ csr_src, int n_edges) {
    int e = blockIdx.x * blockDim.x + threadIdx.x;
    if (e < n_edges) {
        int d = edge_dst[e];
        int pos = atomicAdd(&cursor[d], 1);
        csr_src[pos] = edge_src[e];
    }
}

// ============ MLP: A = relu(relu(feat@W1+b1)@W2+b2); Ay = bf16(A*dinv) ============

__global__ __launch_bounds__(256) void mlp_kernel(const float* __restrict__ feat,
        const float* __restrict__ W1, const float* __restrict__ b1,
        const float* __restrict__ W2, const float* __restrict__ b2,
        const float* __restrict__ dinv,
        float* __restrict__ A, u16* __restrict__ Ay, int n) {
    __shared__ float sW1[FEAT * EMB];   // 32KB
    __shared__ float sBuf[64 * FEAT];   // 32KB
    int tid = threadIdx.x;
    int row0 = blockIdx.x * 64;

    for (int i = tid; i < FEAT * EMB; i += 256) sW1[i] = W1[i];
    for (int i = tid; i < 64 * FEAT; i += 256) {
        int r = i >> 7, c = i & 127;
        int gr = row0 + r;
        sBuf[i] = (gr < n) ? feat[(size_t)gr * FEAT + c] : 0.0f;
    }
    __syncthreads();

    int tx = tid & 15, ty = tid >> 4;
    float4 b1v = *(const float4*)&b1[tx * 4];
    float acc[4][4];
    #pragma unroll
    for (int i = 0; i < 4; ++i) { acc[i][0]=b1v.x; acc[i][1]=b1v.y; acc[i][2]=b1v.z; acc[i][3]=b1v.w; }

    #pragma unroll 4
    for (int k4 = 0; k4 < FEAT / 4; ++k4) {
        float4 a4[4];
        #pragma unroll
        for (int i = 0; i < 4; ++i)
            a4[i] = *(const float4*)&sBuf[(ty * 4 + i) * FEAT + k4 * 4];
        #pragma unroll
        for (int kk = 0; kk < 4; ++kk) {
            float4 bv = *(const float4*)&sW1[(k4 * 4 + kk) * EMB + tx * 4];
            #pragma unroll
            for (int i = 0; i < 4; ++i) {
                float a = ((const float*)&a4[i])[kk];
                acc[i][0] = fmaf(a, bv.x, acc[i][0]);
                acc[i][1] = fmaf(a, bv.y, acc[i][1]);
                acc[i][2] = fmaf(a, bv.z, acc[i][2]);
                acc[i][3] = fmaf(a, bv.w, acc[i][3]);
            }
        }
    }
    __syncthreads();

    float* sH = sBuf;
    float* sW2p = sBuf + 64 * EMB;
    #pragma unroll
    for (int i = 0; i < 4; ++i)
        #pragma unroll
        for (int j = 0; j < 4; ++j)
            sH[(ty * 4 + i) * EMB + tx * 4 + j] = fmaxf(acc[i][j], 0.0f);
    for (int i = tid; i < EMB * EMB; i += 256) sW2p[i] = W2[i];
    __syncthreads();

    float4 b2v = *(const float4*)&b2[tx * 4];
    float acc2[4][4];
    #pragma unroll
    for (int i = 0; i < 4; ++i) { acc2[i][0]=b2v.x; acc2[i][1]=b2v.y; acc2[i][2]=b2v.z; acc2[i][3]=b2v.w; }

    #pragma unroll 4
    for (int k4 = 0; k4 < EMB / 4; ++k4) {
        float4 a4[4];
        #pragma unroll
        for (int i = 0; i < 4; ++i)
            a4[i] = *(const float4*)&sH[(ty * 4 + i) * EMB + k4 * 4];
        #pragma unroll
        for (int kk = 0; kk < 4; ++kk) {
            float4 bv = *(const float4*)&sW2p[(k4 * 4 + kk) * EMB + tx * 4];
            #pragma unroll
            for (int i = 0; i < 4; ++i) {
                float a = ((const float*)&a4[i])[kk];
                acc2[i][0] = fmaf(a, bv.x, acc2[i][0]);
                acc2[i][1] = fmaf(a, bv.y, acc2[i][1]);
                acc2[i][2] = fmaf(a, bv.z, acc2[i][2]);
                acc2[i][3] = fmaf(a, bv.w, acc2[i][3]);
            }
        }
    }

    #pragma unroll
    for (int i = 0; i < 4; ++i) {
        int gr = row0 + ty * 4 + i;
        if (gr < n) {
            float di = dinv[gr];
            float4 o;
            o.x = fmaxf(acc2[i][0], 0.0f); o.y = fmaxf(acc2[i][1], 0.0f);
            o.z = fmaxf(acc2[i][2], 0.0f); o.w = fmaxf(acc2[i][3], 0.0f);
            *(float4*)&A[(size_t)gr * EMB + tx * 4] = o;
            ushort4 oy;
            oy.x = f2bf(o.x * di); oy.y = f2bf(o.y * di);
            oy.z = f2bf(o.z * di); oy.w = f2bf(o.w * di);
            *(ushort4*)&Ay[(size_t)gr * EMB + tx * 4] = oy;
        }
    }
}

// ============ Laplacian kernels ============
// y = bf16(x*dinv). lap(x)[i] = x[i] - dinv[i]*sum_{src->i} y[src]
// 16 lanes per node; x float4/lane, y ushort4(bf16)/lane.

__global__ __launch_bounds__(256) void lap_kernel(
        const float4* __restrict__ x, const ushort4* __restrict__ y,
        float4* __restrict__ Bx, ushort4* __restrict__ By,
        const int* __restrict__ rowptr, const int* __restrict__ csr,
        const float* __restrict__ dinv, int n) {
    int tid = blockIdx.x * blockDim.x + threadIdx.x;
    int g = tid >> 4, gl = tid & 15;
    if (g >= n) return;
    int s = rowptr[g], e = rowptr[g + 1];
    float4 acc = {0.f, 0.f, 0.f, 0.f};
    for (int p = s; p < e; ++p) {
        int src = csr[p];
        ushort4 v = y[(size_t)src * 16 + gl];
        acc.x += bf2f(v.x); acc.y += bf2f(v.y);
        acc.z += bf2f(v.z); acc.w += bf2f(v.w);
    }
    float di = dinv[g];
    float4 xv = x[(size_t)g * 16 + gl];
    float4 o;
    o.x = xv.x - acc.x * di; o.y = xv.y - acc.y * di;
    o.z = xv.z - acc.z * di; o.w = xv.w - acc.w * di;
    Bx[(size_t)g * 16 + gl] = o;
    ushort4 oy;
    oy.x = f2bf(o.x * di); oy.y = f2bf(o.y * di);
    oy.z = f2bf(o.z * di); oy.w = f2bf(o.w * di);
    By[(size_t)g * 16 + gl] = oy;
}

// A = t0*A + t1*B + t2*(B - dinv*sum By[src]); Ay = bf16(A*dinv)
// skip_a: t0 == 0 -> don't read Ax
__global__ __launch_bounds__(256) void theta_kernel(
        float4* __restrict__ Ax, ushort4* __restrict__ Ay,
        const float4* __restrict__ Bx, const ushort4* __restrict__ By,
        const int* __restrict__ rowptr, const int* __restrict__ csr,
        const float* __restrict__ dinv, int n, float t0, float t1, float t2, int skip_a) {
    int tid = blockIdx.x * blockDim.x + threadIdx.x;
    int g = tid >> 4, gl = tid & 15;
    if (g >= n) return;
    int s = rowptr[g], e = rowptr[g + 1];
    float4 acc = {0.f, 0.f, 0.f, 0.f};
    for (int p = s; p < e; ++p) {
        int src = csr[p];
        ushort4 v = By[(size_t)src * 16 + gl];
        acc.x += bf2f(v.x); acc.y += bf2f(v.y);
        acc.z += bf2f(v.z); acc.w += bf2f(v.w);
    }
    float di = dinv[g];
    float4 bv = Bx[(size_t)g * 16 + gl];
    float4 av = {0.f, 0.f, 0.f, 0.f};
    if (!skip_a) av = Ax[(size_t)g * 16 + gl];
    float4 lapB;
    lapB.x = bv.x - acc.x * di; lapB.y = bv.y - acc.y * di;
    lapB.z = bv.z - acc.z * di; lapB.w = bv.w - acc.w * di;
    float4 o;
    o.x = t0 * av.x + t1 * bv.x + t2 * lapB.x;
    o.y = t0 * av.y + t1 * bv.y + t2 * lapB.y;
    o.z = t0 * av.z + t1 * bv.z + t2 * lapB.z;
    o.w = t0 * av.w + t1 * bv.w + t2 * lapB.w;
    Ax[(size_t)g * 16 + gl] = o;
    ushort4 oy;
    oy.x = f2bf(o.x * di); oy.y = f2bf(o.y * di);
    oy.z = f2bf(o.z * di); oy.w = f2bf(o.w * di);
    Ay[(size_t)g * 16 + gl] = oy;
}

// Last conv (theta = (0,0,t2)) restricted to the selected output nodes:
// hsel[i] = t2 * (Bx[node] - dinv[node]*sum By[src])
__global__ __launch_bounds__(256) void theta_sel_kernel(
        const float4* __restrict__ Bx, const ushort4* __restrict__ By,
        const int* __restrict__ rowptr, const int* __restrict__ csr,
        const float* __restrict__ dinv, const int* __restrict__ nodes,
        float4* __restrict__ hsel, int n, float t2) {
    int tid = blockIdx.x * blockDim.x + threadIdx.x;
    int i = tid >> 4, gl = tid & 15;
    if (i >= n) return;
    int g = nodes[i];
    int s = rowptr[g], e = rowptr[g + 1];
    float4 acc = {0.f, 0.f, 0.f, 0.f};
    for (int p = s; p < e; ++p) {
        int src = csr[p];
        ushort4 v = By[(size_t)src * 16 + gl];
        acc.x += bf2f(v.x); acc.y += bf2f(v.y);
        acc.z += bf2f(v.z); acc.w += bf2f(v.w);
    }
    float di = dinv[g];
    float4 bv = Bx[(size_t)g * 16 + gl];
    float4 o;
    o.x = t2 * (bv.x - acc.x * di); o.y = t2 * (bv.y - acc.y * di);
    o.z = t2 * (bv.z - acc.z * di); o.w = t2 * (bv.w - acc.w * di);
    hsel[(size_t)i * 16 + gl] = o;
}

// ============ Final stage 1: vtmp = feat[node] + hsel[i]@W3 + b3 ; scores ============

__global__ __launch_bounds__(256) void final1_kernel(const float* __restrict__ feat,
        const float* __restrict__ hsel, const float* __restrict__ W3, const float* __restrict__ b3,
        const float* __restrict__ Wclf, const float* __restrict__ bclf,
        const int* __restrict__ nodes, float* __restrict__ vtmp, float* __restrict__ scores,
        int n) {
    __shared__ float sW3[EMB * FEAT];    // 32KB
    __shared__ float sHt[64 * 68];       // 17KB padded
    __shared__ float sWclf[FEAT * 2];
    __shared__ float sb3[FEAT];
    __shared__ float sbclf[2];
    __shared__ int sNodes[64];
    int tid = threadIdx.x;
    int base = blockIdx.x * 64;

    for (int i = tid; i < EMB * FEAT; i += 256) sW3[i] = W3[i];
    for (int i = tid; i < FEAT * 2; i += 256) sWclf[i] = Wclf[i];
    if (tid < FEAT) sb3[tid] = b3[tid];
    if (tid < 2) sbclf[tid] = bclf[tid];
    if (tid < 64) {
        int gi = base + tid;
        sNodes[tid] = (gi < n) ? nodes[gi] : 0;
    }
    // hsel rows are contiguous by output index -> coalesced
    for (int it = 0; it < 16; ++it) {
        int id = it * 256 + tid;
        int r = id >> 6, c = id & 63;
        int gi = base + r;
        sHt[r * 68 + c] = (gi < n) ? hsel[(size_t)gi * EMB + c] : 0.0f;
    }
    __syncthreads();

    // scores
    {
        int wv = tid >> 6, ln = tid & 63;
        float bc0 = sbclf[0], bc1 = sbclf[1];
        for (int q = 0; q < 16; ++q) {
            int r = wv * 16 + q;
            int nd = sNodes[r];
            float f0 = feat[(size_t)nd * FEAT + ln];
            float f1 = feat[(size_t)nd * FEAT + 64 + ln];
            float p0 = f0 * sWclf[ln * 2]     + f1 * sWclf[(64 + ln) * 2];
            float p1 = f0 * sWclf[ln * 2 + 1] + f1 * sWclf[(64 + ln) * 2 + 1];
            #pragma unroll
            for (int off = 32; off > 0; off >>= 1) {
                p0 += __shfl_xor(p0, off);
                p1 += __shfl_xor(p1, off);
            }
            int gi = base + r;
            if (ln == 0 && gi < n) {
                scores[(size_t)gi * 2]     = p0 + bc0;
                scores[(size_t)gi * 2 + 1] = p1 + bc1;
            }
        }
    }

    int tx = tid & 31, ty = tid >> 5;
    float acc[8][4];
    #pragma unroll
    for (int i = 0; i < 8; ++i)
        #pragma unroll
        for (int j = 0; j < 4; ++j) acc[i][j] = 0.0f;

    #pragma unroll 2
    for (int k4 = 0; k4 < EMB / 4; ++k4) {
        float4 a4[8];
        #pragma unroll
        for (int i = 0; i < 8; ++i)
            a4[i] = *(const float4*)&sHt[(ty * 8 + i) * 68 + k4 * 4];
        #pragma unroll
        for (int kk = 0; kk < 4; ++kk) {
            float4 bv = *(const float4*)&sW3[(k4 * 4 + kk) * FEAT + tx * 4];
            #pragma unroll
            for (int i = 0; i < 8; ++i) {
                float a = ((const float*)&a4[i])[kk];
                acc[i][0] = fmaf(a, bv.x, acc[i][0]);
                acc[i][1] = fmaf(a, bv.y, acc[i][1]);
                acc[i][2] = fmaf(a, bv.z, acc[i][2]);
                acc[i][3] = fmaf(a, bv.w, acc[i][3]);
            }
        }
    }

    float4 b3v = *(const float4*)&sb3[tx * 4];
    #pragma unroll
    for (int i = 0; i < 8; ++i) {
        int r = ty * 8 + i;
        int gi = base + r;
        int nd = sNodes[r];
        float4 fv = *(const float4*)&feat[(size_t)nd * FEAT + tx * 4];
        float4 o;
        o.x = acc[i][0] + b3v.x + fv.x;
        o.y = acc[i][1] + b3v.y + fv.y;
        o.z = acc[i][2] + b3v.z + fv.z;
        o.w = acc[i][3] + b3v.w + fv.w;
        if (gi < n) *(float4*)&vtmp[(size_t)gi * FEAT + tx * 4] = o;
    }
}

// ============ Final stage 2: out = relu(vtmp @ weight) ============

__global__ __launch_bounds__(256) void final2_kernel(const float* __restrict__ vtmp,
        const float* __restrict__ weight, float* __restrict__ outc, int n) {
    __shared__ float sWt[FEAT * EMB];   // 32KB
    __shared__ float sV[64 * FEAT];     // 32KB
    int tid = threadIdx.x;
    int base = blockIdx.x * 64;
    for (int i = tid; i < FEAT * EMB; i += 256) sWt[i] = weight[i];
    for (int i = tid; i < 64 * FEAT; i += 256) {
        int r = i >> 7, c = i & 127;
        int gi = base + r;
        sV[i] = (gi < n) ? vtmp[(size_t)gi * FEAT + c] : 0.0f;
    }
    __syncthreads();

    int tx = tid & 15, ty = tid >> 4;
    float acc[4][4];
    #pragma unroll
    for (int i = 0; i < 4; ++i)
        #pragma unroll
        for (int j = 0; j < 4; ++j) acc[i][j] = 0.0f;

    #pragma unroll 4
    for (int k4 = 0; k4 < FEAT / 4; ++k4) {
        float4 a4[4];
        #pragma unroll
        for (int i = 0; i < 4; ++i)
            a4[i] = *(const float4*)&sV[(ty * 4 + i) * FEAT + k4 * 4];
        #pragma unroll
        for (int kk = 0; kk < 4; ++kk) {
            float4 bv = *(const float4*)&sWt[(k4 * 4 + kk) * EMB + tx * 4];
            #pragma unroll
            for (int i = 0; i < 4; ++i) {
                float a = ((const float*)&a4[i])[kk];
                acc[i][0] = fmaf(a, bv.x, acc[i][0]);
                acc[i][1] = fmaf(a, bv.y, acc[i][1]);
                acc[i][2] = fmaf(a, bv.z, acc[i][2]);
                acc[i][3] = fmaf(a, bv.w, acc[i][3]);
            }
        }
    }

    #pragma unroll
    for (int i = 0; i < 4; ++i) {
        int gi = base + ty * 4 + i;
        if (gi < n) {
            float4 o;
            o.x = fmaxf(acc[i][0], 0.0f); o.y = fmaxf(acc[i][1], 0.0f);
            o.z = fmaxf(acc[i][2], 0.0f); o.w = fmaxf(acc[i][3], 0.0f);
            *(float4*)&outc[(size_t)gi * EMB + tx * 4] = o;
        }
    }
}

// ============ launch ============

extern "C" void kernel_launch(void* const* d_in, const int* in_sizes, int n_in,
                              void* d_out, int out_size, void* d_ws, size_t ws_size,
                              hipStream_t stream) {
    const float* feat   = (const float*)d_in[0];
    const float* Wclf   = (const float*)d_in[1];
    const float* bclf   = (const float*)d_in[2];
    const float* W1     = (const float*)d_in[3];
    const float* b1     = (const float*)d_in[4];
    const float* W2     = (const float*)d_in[5];
    const float* b2     = (const float*)d_in[6];
    const float* W3     = (const float*)d_in[7];
    const float* b3     = (const float*)d_in[8];
    const float* weight = (const float*)d_in[9];
    const int* nodes    = (const int*)d_in[10];
    // d_in[11] = r1_neighs: DEAD (AGG_WEIGHT[0] == 0.0)
    const int* edge_src = (const int*)d_in[12];
    const int* edge_dst = (const int*)d_in[13];

    int n       = in_sizes[10];        // 8192
    int n_edges = in_sizes[12];        // 1600000
    int N       = in_sizes[0] / FEAT;  // 50000

    char* ws = (char*)d_ws;
    size_t off = 0;
    auto alloc = [&](size_t bytes) -> void* {
        void* p = ws + off;
        off = (off + bytes + 255) & ~(size_t)255;
        return p;
    };
    int*   deg    = (int*)  alloc((size_t)N * 4);
    int*   cursor = (int*)  alloc((size_t)N * 4);
    int*   rowptr = (int*)  alloc((size_t)(N + 1) * 4);
    float* dinv   = (float*)alloc((size_t)N * 4);
    int*   bsum   = (int*)  alloc(256 * 4);
    int*   boff   = (int*)  alloc(256 * 4);
    int*   csr    = (int*)  alloc((size_t)n_edges * 4);
    float* Axf    = (float*)alloc((size_t)N * EMB * 4);
    u16*   Ayf    = (u16*)  alloc((size_t)N * EMB * 2);
    float* Bxf    = (float*)alloc((size_t)N * EMB * 4);
    u16*   Byf    = (u16*)  alloc((size_t)N * EMB * 2);
    float* hsel   = (float*)alloc((size_t)n * EMB * 4);
    float* vtmp   = (float*)alloc((size_t)n * FEAT * 4);

    float* out_combined = (float*)d_out;                       // [n, 64]
    float* out_scores   = out_combined + (size_t)n * EMB;      // [n, 2]

    hipMemsetAsync(deg, 0, (size_t)N * 4, stream);

    int eb = (n_edges + 255) / 256;
    int sb = (N + 255) / 256;
    count_deg_kernel<<<eb, 256, 0, stream>>>(edge_dst, deg, n_edges);
    block_sum_kernel<<<sb, 256, 0, stream>>>(deg, bsum, N);
    scan_bsum_kernel<<<1, 256, 0, stream>>>(bsum, boff, sb);
    scan_fill_kernel<<<sb, 256, 0, stream>>>(deg, boff, rowptr, dinv, N);
    hipMemcpyAsync(cursor, rowptr, (size_t)N * 4, hipMemcpyDeviceToDevice, stream);
    fill_csr_kernel<<<eb, 256, 0, stream>>>(edge_src, edge_dst, cursor, csr, n_edges);

    int mb = (N + 63) / 64;
    mlp_kernel<<<mb, 256, 0, stream>>>(feat, W1, b1, W2, b2, dinv, Axf, Ayf, N);

    int lb = ((size_t)N * 16 + 255) / 256;
    // conv 0: theta = (3, -3, 0.75)
    lap_kernel<<<lb, 256, 0, stream>>>((const float4*)Axf, (const ushort4*)Ayf,
                                       (float4*)Bxf, (ushort4*)Byf, rowptr, csr, dinv, N);
    theta_kernel<<<lb, 256, 0, stream>>>((float4*)Axf, (ushort4*)Ayf,
                                         (const float4*)Bxf, (const ushort4*)Byf,
                                         rowptr, csr, dinv, N, 3.f, -3.f, 0.75f, 0);
    // conv 1: theta = (0, 3, -1.5)
    lap_kernel<<<lb, 256, 0, stream>>>((const float4*)Axf, (const ushort4*)Ayf,
                                       (float4*)Bxf, (ushort4*)Byf, rowptr, csr, dinv, N);
    theta_kernel<<<lb, 256, 0, stream>>>((float4*)Axf, (ushort4*)Ayf,
                                         (const float4*)Bxf, (const ushort4*)Byf,
                                         rowptr, csr, dinv, N, 0.f, 3.f, -1.5f, 1);
    // conv 2: theta = (0, 0, 0.75) -> only needed at `nodes`
    lap_kernel<<<lb, 256, 0, stream>>>((const float4*)Axf, (const ushort4*)Ayf,
                                       (float4*)Bxf, (ushort4*)Byf, rowptr, csr, dinv, N);
    int selb = ((size_t)n * 16 + 255) / 256;
    theta_sel_kernel<<<selb, 256, 0, stream>>>((const float4*)Bxf, (const ushort4*)Byf,
                                               rowptr, csr, dinv, nodes,
                                               (float4*)hsel, n, 0.75f);

    int fb = (n + 63) / 64;
    final1_kernel<<<fb, 256, 0, stream>>>(feat, hsel, W3, b3, Wclf, bclf, nodes,
                                          vtmp, out_scores, n);
    final2_kernel<<<fb, 256, 0, stream>>>(vtmp, weight, out_combined, n);
}

// Round 6
// 518.289 us; speedup vs baseline: 2.6220x; 1.3315x over previous
//
#include <hip/hip_runtime.h>

#define FEAT 128
#define EMB 64

typedef unsigned short u16;

__device__ inline u16 f2bf(float f) {
    unsigned u = __float_as_uint(f);
    unsigned r = (u + 0x7FFFu + ((u >> 16) & 1u)) >> 16;
    return (u16)r;
}
__device__ inline unsigned pack2(float lo, float hi) {
    return ((unsigned)f2bf(hi) << 16) | (unsigned)f2bf(lo);
}
__device__ inline void acc8(float* acc, uint4 v) {
    acc[0] += __uint_as_float(v.x << 16);
    acc[1] += __uint_as_float(v.x & 0xFFFF0000u);
    acc[2] += __uint_as_float(v.y << 16);
    acc[3] += __uint_as_float(v.y & 0xFFFF0000u);
    acc[4] += __uint_as_float(v.z << 16);
    acc[5] += __uint_as_float(v.z & 0xFFFF0000u);
    acc[6] += __uint_as_float(v.w << 16);
    acc[7] += __uint_as_float(v.w & 0xFFFF0000u);
}

// ============ CSR build ============

__global__ void count_deg_kernel(const int* __restrict__ edge_dst, int* __restrict__ deg, int n_edges) {
    int e = blockIdx.x * blockDim.x + threadIdx.x;
    if (e < n_edges) atomicAdd(&deg[edge_dst[e]], 1);
}

__global__ void block_sum_kernel(const int* __restrict__ deg, int* __restrict__ bsum, int n) {
    __shared__ int sd[256];
    int t = threadIdx.x;
    int i = blockIdx.x * 256 + t;
    sd[t] = (i < n) ? deg[i] : 0;
    __syncthreads();
    for (int off = 128; off > 0; off >>= 1) {
        if (t < off) sd[t] += sd[t + off];
        __syncthreads();
    }
    if (t == 0) bsum[blockIdx.x] = sd[0];
}

__global__ void scan_bsum_kernel(const int* __restrict__ bsum, int* __restrict__ boff, int nb) {
    __shared__ int sd[256];
    int t = threadIdx.x;
    int v = (t < nb) ? bsum[t] : 0;
    sd[t] = v;
    __syncthreads();
    for (int off = 1; off < 256; off <<= 1) {
        int u = (t >= off) ? sd[t - off] : 0;
        __syncthreads();
        sd[t] += u;
        __syncthreads();
    }
    if (t < nb) boff[t] = sd[t] - v;
}

__global__ void scan_fill_kernel(const int* __restrict__ deg, const int* __restrict__ boff,
                                 int* __restrict__ rowptr, float* __restrict__ dinv, int n) {
    __shared__ int sd[256];
    int t = threadIdx.x;
    int i = blockIdx.x * 256 + t;
    int v = (i < n) ? deg[i] : 0;
    sd[t] = v;
    __syncthreads();
    for (int off = 1; off < 256; off <<= 1) {
        int u = (t >= off) ? sd[t - off] : 0;
        __syncthreads();
        sd[t] += u;
        __syncthreads();
    }
    if (i < n) {
        rowptr[i + 1] = boff[blockIdx.x] + sd[t];
        dinv[i] = rsqrtf(fmaxf((float)v, 1.0f));
    }
    if (i == 0) rowptr[0] = 0;
}

// cursor pre-initialized to rowptr via d2d copy; csr entries are u16 (N < 65536)
__global__ void fill_csr_kernel(const int* __restrict__ edge_src, const int* __restrict__ edge_dst,
                                int* __restrict__ cursor, u16* __restrict__ csr_src, int n_edges) {
    int e = blockIdx.x * blockDim.x + threadIdx.x;
    if (e < n_edges) {
        int d = edge_dst[e];
        int pos = atomicAdd(&cursor[d], 1);
        csr_src[pos] = (u16)edge_src[e];
    }
}

// ============ MLP: A = relu(relu(feat@W1+b1)@W2+b2); Ay = bf16(A*dinv) ============

__global__ __launch_bounds__(256) void mlp_kernel(const float* __restrict__ feat,
        const float* __restrict__ W1, const float* __restrict__ b1,
        const float* __restrict__ W2, const float* __restrict__ b2,
        const float* __restrict__ dinv,
        float* __restrict__ A, u16* __restrict__ Ay, int n) {
    __shared__ float sW1[FEAT * EMB];   // 32KB
    __shared__ float sBuf[64 * FEAT];   // 32KB
    int tid = threadIdx.x;
    int row0 = blockIdx.x * 64;

    for (int i = tid; i < FEAT * EMB; i += 256) sW1[i] = W1[i];
    for (int i = tid; i < 64 * FEAT; i += 256) {
        int r = i >> 7, c = i & 127;
        int gr = row0 + r;
        sBuf[i] = (gr < n) ? feat[(size_t)gr * FEAT + c] : 0.0f;
    }
    __syncthreads();

    int tx = tid & 15, ty = tid >> 4;
    float4 b1v = *(const float4*)&b1[tx * 4];
    float acc[4][4];
    #pragma unroll
    for (int i = 0; i < 4; ++i) { acc[i][0]=b1v.x; acc[i][1]=b1v.y; acc[i][2]=b1v.z; acc[i][3]=b1v.w; }

    #pragma unroll 4
    for (int k4 = 0; k4 < FEAT / 4; ++k4) {
        float4 a4[4];
        #pragma unroll
        for (int i = 0; i < 4; ++i)
            a4[i] = *(const float4*)&sBuf[(ty * 4 + i) * FEAT + k4 * 4];
        #pragma unroll
        for (int kk = 0; kk < 4; ++kk) {
            float4 bv = *(const float4*)&sW1[(k4 * 4 + kk) * EMB + tx * 4];
            #pragma unroll
            for (int i = 0; i < 4; ++i) {
                float a = ((const float*)&a4[i])[kk];
                acc[i][0] = fmaf(a, bv.x, acc[i][0]);
                acc[i][1] = fmaf(a, bv.y, acc[i][1]);
                acc[i][2] = fmaf(a, bv.z, acc[i][2]);
                acc[i][3] = fmaf(a, bv.w, acc[i][3]);
            }
        }
    }
    __syncthreads();

    float* sH = sBuf;
    float* sW2p = sBuf + 64 * EMB;
    #pragma unroll
    for (int i = 0; i < 4; ++i)
        #pragma unroll
        for (int j = 0; j < 4; ++j)
            sH[(ty * 4 + i) * EMB + tx * 4 + j] = fmaxf(acc[i][j], 0.0f);
    for (int i = tid; i < EMB * EMB; i += 256) sW2p[i] = W2[i];
    __syncthreads();

    float4 b2v = *(const float4*)&b2[tx * 4];
    float acc2[4][4];
    #pragma unroll
    for (int i = 0; i < 4; ++i) { acc2[i][0]=b2v.x; acc2[i][1]=b2v.y; acc2[i][2]=b2v.z; acc2[i][3]=b2v.w; }

    #pragma unroll 4
    for (int k4 = 0; k4 < EMB / 4; ++k4) {
        float4 a4[4];
        #pragma unroll
        for (int i = 0; i < 4; ++i)
            a4[i] = *(const float4*)&sH[(ty * 4 + i) * EMB + k4 * 4];
        #pragma unroll
        for (int kk = 0; kk < 4; ++kk) {
            float4 bv = *(const float4*)&sW2p[(k4 * 4 + kk) * EMB + tx * 4];
            #pragma unroll
            for (int i = 0; i < 4; ++i) {
                float a = ((const float*)&a4[i])[kk];
                acc2[i][0] = fmaf(a, bv.x, acc2[i][0]);
                acc2[i][1] = fmaf(a, bv.y, acc2[i][1]);
                acc2[i][2] = fmaf(a, bv.z, acc2[i][2]);
                acc2[i][3] = fmaf(a, bv.w, acc2[i][3]);
            }
        }
    }

    #pragma unroll
    for (int i = 0; i < 4; ++i) {
        int gr = row0 + ty * 4 + i;
        if (gr < n) {
            float di = dinv[gr];
            float4 o;
            o.x = fmaxf(acc2[i][0], 0.0f); o.y = fmaxf(acc2[i][1], 0.0f);
            o.z = fmaxf(acc2[i][2], 0.0f); o.w = fmaxf(acc2[i][3], 0.0f);
            *(float4*)&A[(size_t)gr * EMB + tx * 4] = o;
            uint2 oy;
            oy.x = pack2(o.x * di, o.y * di);
            oy.y = pack2(o.z * di, o.w * di);
            *(uint2*)&Ay[(size_t)gr * EMB + tx * 4] = oy;
        }
    }
}

// ============ Laplacian kernels ============
// y = bf16(x*dinv) packed 2/uint. lap(x)[i] = x[i] - dinv[i]*sum_{src->i} y[src]
// 8 lanes/node, uint4 (8 bf16) per lane, edge loop unrolled x4 for ILP.

__global__ __launch_bounds__(256) void lap_kernel(
        const float4* __restrict__ x, const uint4* __restrict__ y,
        float4* __restrict__ Bx, uint4* __restrict__ By,
        const int* __restrict__ rowptr, const u16* __restrict__ csr,
        const float* __restrict__ dinv, int n) {
    int tid = blockIdx.x * blockDim.x + threadIdx.x;
    int g = tid >> 3, gl = tid & 7;
    if (g >= n) return;
    int s = rowptr[g], e = rowptr[g + 1];
    float acc[8] = {0.f,0.f,0.f,0.f,0.f,0.f,0.f,0.f};
    int p = s;
    for (; p + 3 < e; p += 4) {
        int i0 = csr[p], i1 = csr[p+1], i2 = csr[p+2], i3 = csr[p+3];
        uint4 v0 = y[(size_t)i0 * 8 + gl];
        uint4 v1 = y[(size_t)i1 * 8 + gl];
        uint4 v2 = y[(size_t)i2 * 8 + gl];
        uint4 v3 = y[(size_t)i3 * 8 + gl];
        acc8(acc, v0); acc8(acc, v1); acc8(acc, v2); acc8(acc, v3);
    }
    for (; p < e; ++p) {
        int i0 = csr[p];
        acc8(acc, y[(size_t)i0 * 8 + gl]);
    }
    float di = dinv[g];
    float4 xa = x[(size_t)g * 16 + gl * 2];
    float4 xb = x[(size_t)g * 16 + gl * 2 + 1];
    float4 oa, ob;
    oa.x = xa.x - acc[0] * di; oa.y = xa.y - acc[1] * di;
    oa.z = xa.z - acc[2] * di; oa.w = xa.w - acc[3] * di;
    ob.x = xb.x - acc[4] * di; ob.y = xb.y - acc[5] * di;
    ob.z = xb.z - acc[6] * di; ob.w = xb.w - acc[7] * di;
    Bx[(size_t)g * 16 + gl * 2] = oa;
    Bx[(size_t)g * 16 + gl * 2 + 1] = ob;
    uint4 oy;
    oy.x = pack2(oa.x * di, oa.y * di);
    oy.y = pack2(oa.z * di, oa.w * di);
    oy.z = pack2(ob.x * di, ob.y * di);
    oy.w = pack2(ob.z * di, ob.w * di);
    By[(size_t)g * 8 + gl] = oy;
}

// A = t0*A + t1*B + t2*(B - dinv*sum By[src]); Ay = bf16(A*dinv)
__global__ __launch_bounds__(256) void theta_kernel(
        float4* __restrict__ Ax, uint4* __restrict__ Ay,
        const float4* __restrict__ Bx, const uint4* __restrict__ By,
        const int* __restrict__ rowptr, const u16* __restrict__ csr,
        const float* __restrict__ dinv, int n, float t0, float t1, float t2, int skip_a) {
    int tid = blockIdx.x * blockDim.x + threadIdx.x;
    int g = tid >> 3, gl = tid & 7;
    if (g >= n) return;
    int s = rowptr[g], e = rowptr[g + 1];
    float acc[8] = {0.f,0.f,0.f,0.f,0.f,0.f,0.f,0.f};
    int p = s;
    for (; p + 3 < e; p += 4) {
        int i0 = csr[p], i1 = csr[p+1], i2 = csr[p+2], i3 = csr[p+3];
        uint4 v0 = By[(size_t)i0 * 8 + gl];
        uint4 v1 = By[(size_t)i1 * 8 + gl];
        uint4 v2 = By[(size_t)i2 * 8 + gl];
        uint4 v3 = By[(size_t)i3 * 8 + gl];
        acc8(acc, v0); acc8(acc, v1); acc8(acc, v2); acc8(acc, v3);
    }
    for (; p < e; ++p) {
        int i0 = csr[p];
        acc8(acc, By[(size_t)i0 * 8 + gl]);
    }
    float di = dinv[g];
    float4 ba = Bx[(size_t)g * 16 + gl * 2];
    float4 bb = Bx[(size_t)g * 16 + gl * 2 + 1];
    float4 aa = {0.f,0.f,0.f,0.f}, ab = {0.f,0.f,0.f,0.f};
    if (!skip_a) {
        aa = Ax[(size_t)g * 16 + gl * 2];
        ab = Ax[(size_t)g * 16 + gl * 2 + 1];
    }
    float4 oa, ob;
    oa.x = t0 * aa.x + t1 * ba.x + t2 * (ba.x - acc[0] * di);
    oa.y = t0 * aa.y + t1 * ba.y + t2 * (ba.y - acc[1] * di);
    oa.z = t0 * aa.z + t1 * ba.z + t2 * (ba.z - acc[2] * di);
    oa.w = t0 * aa.w + t1 * ba.w + t2 * (ba.w - acc[3] * di);
    ob.x = t0 * ab.x + t1 * bb.x + t2 * (bb.x - acc[4] * di);
    ob.y = t0 * ab.y + t1 * bb.y + t2 * (bb.y - acc[5] * di);
    ob.z = t0 * ab.z + t1 * bb.z + t2 * (bb.z - acc[6] * di);
    ob.w = t0 * ab.w + t1 * bb.w + t2 * (bb.w - acc[7] * di);
    Ax[(size_t)g * 16 + gl * 2] = oa;
    Ax[(size_t)g * 16 + gl * 2 + 1] = ob;
    uint4 oy;
    oy.x = pack2(oa.x * di, oa.y * di);
    oy.y = pack2(oa.z * di, oa.w * di);
    oy.z = pack2(ob.x * di, ob.y * di);
    oy.w = pack2(ob.z * di, ob.w * di);
    Ay[(size_t)g * 8 + gl] = oy;
}

// Last conv (theta=(0,0,t2)) only at selected nodes: hsel[i] = t2*lap(B)[node_i]
__global__ __launch_bounds__(256) void theta_sel_kernel(
        const float4* __restrict__ Bx, const uint4* __restrict__ By,
        const int* __restrict__ rowptr, const u16* __restrict__ csr,
        const float* __restrict__ dinv, const int* __restrict__ nodes,
        float4* __restrict__ hsel, int n, float t2) {
    int tid = blockIdx.x * blockDim.x + threadIdx.x;
    int i = tid >> 3, gl = tid & 7;
    if (i >= n) return;
    int g = nodes[i];
    int s = rowptr[g], e = rowptr[g + 1];
    float acc[8] = {0.f,0.f,0.f,0.f,0.f,0.f,0.f,0.f};
    int p = s;
    for (; p + 3 < e; p += 4) {
        int i0 = csr[p], i1 = csr[p+1], i2 = csr[p+2], i3 = csr[p+3];
        uint4 v0 = By[(size_t)i0 * 8 + gl];
        uint4 v1 = By[(size_t)i1 * 8 + gl];
        uint4 v2 = By[(size_t)i2 * 8 + gl];
        uint4 v3 = By[(size_t)i3 * 8 + gl];
        acc8(acc, v0); acc8(acc, v1); acc8(acc, v2); acc8(acc, v3);
    }
    for (; p < e; ++p) {
        int i0 = csr[p];
        acc8(acc, By[(size_t)i0 * 8 + gl]);
    }
    float di = dinv[g];
    float4 ba = Bx[(size_t)g * 16 + gl * 2];
    float4 bb = Bx[(size_t)g * 16 + gl * 2 + 1];
    float4 oa, ob;
    oa.x = t2 * (ba.x - acc[0] * di); oa.y = t2 * (ba.y - acc[1] * di);
    oa.z = t2 * (ba.z - acc[2] * di); oa.w = t2 * (ba.w - acc[3] * di);
    ob.x = t2 * (bb.x - acc[4] * di); ob.y = t2 * (bb.y - acc[5] * di);
    ob.z = t2 * (bb.z - acc[6] * di); ob.w = t2 * (bb.w - acc[7] * di);
    hsel[(size_t)i * 16 + gl * 2] = oa;
    hsel[(size_t)i * 16 + gl * 2 + 1] = ob;
}

// ============ Final stage 1: vtmp = feat[node] + hsel[i]@W3 + b3 ; scores ============

__global__ __launch_bounds__(256) void final1_kernel(const float* __restrict__ feat,
        const float* __restrict__ hsel, const float* __restrict__ W3, const float* __restrict__ b3,
        const float* __restrict__ Wclf, const float* __restrict__ bclf,
        const int* __restrict__ nodes, float* __restrict__ vtmp, float* __restrict__ scores,
        int n) {
    __shared__ float sW3[EMB * FEAT];    // 32KB
    __shared__ float sHt[64 * 68];       // 17KB padded
    __shared__ float sWclf[FEAT * 2];
    __shared__ float sb3[FEAT];
    __shared__ float sbclf[2];
    __shared__ int sNodes[64];
    int tid = threadIdx.x;
    int base = blockIdx.x * 64;

    for (int i = tid; i < EMB * FEAT; i += 256) sW3[i] = W3[i];
    for (int i = tid; i < FEAT * 2; i += 256) sWclf[i] = Wclf[i];
    if (tid < FEAT) sb3[tid] = b3[tid];
    if (tid < 2) sbclf[tid] = bclf[tid];
    if (tid < 64) {
        int gi = base + tid;
        sNodes[tid] = (gi < n) ? nodes[gi] : 0;
    }
    for (int it = 0; it < 16; ++it) {
        int id = it * 256 + tid;
        int r = id >> 6, c = id & 63;
        int gi = base + r;
        sHt[r * 68 + c] = (gi < n) ? hsel[(size_t)gi * EMB + c] : 0.0f;
    }
    __syncthreads();

    {
        int wv = tid >> 6, ln = tid & 63;
        float bc0 = sbclf[0], bc1 = sbclf[1];
        for (int q = 0; q < 16; ++q) {
            int r = wv * 16 + q;
            int nd = sNodes[r];
            float f0 = feat[(size_t)nd * FEAT + ln];
            float f1 = feat[(size_t)nd * FEAT + 64 + ln];
            float p0 = f0 * sWclf[ln * 2]     + f1 * sWclf[(64 + ln) * 2];
            float p1 = f0 * sWclf[ln * 2 + 1] + f1 * sWclf[(64 + ln) * 2 + 1];
            #pragma unroll
            for (int off = 32; off > 0; off >>= 1) {
                p0 += __shfl_xor(p0, off);
                p1 += __shfl_xor(p1, off);
            }
            int gi = base + r;
            if (ln == 0 && gi < n) {
                scores[(size_t)gi * 2]     = p0 + bc0;
                scores[(size_t)gi * 2 + 1] = p1 + bc1;
            }
        }
    }

    int tx = tid & 31, ty = tid >> 5;
    float acc[8][4];
    #pragma unroll
    for (int i = 0; i < 8; ++i)
        #pragma unroll
        for (int j = 0; j < 4; ++j) acc[i][j] = 0.0f;

    #pragma unroll 2
    for (int k4 = 0; k4 < EMB / 4; ++k4) {
        float4 a4[8];
        #pragma unroll
        for (int i = 0; i < 8; ++i)
            a4[i] = *(const float4*)&sHt[(ty * 8 + i) * 68 + k4 * 4];
        #pragma unroll
        for (int kk = 0; kk < 4; ++kk) {
            float4 bv = *(const float4*)&sW3[(k4 * 4 + kk) * FEAT + tx * 4];
            #pragma unroll
            for (int i = 0; i < 8; ++i) {
                float a = ((const float*)&a4[i])[kk];
                acc[i][0] = fmaf(a, bv.x, acc[i][0]);
                acc[i][1] = fmaf(a, bv.y, acc[i][1]);
                acc[i][2] = fmaf(a, bv.z, acc[i][2]);
                acc[i][3] = fmaf(a, bv.w, acc[i][3]);
            }
        }
    }

    float4 b3v = *(const float4*)&sb3[tx * 4];
    #pragma unroll
    for (int i = 0; i < 8; ++i) {
        int r = ty * 8 + i;
        int gi = base + r;
        int nd = sNodes[r];
        float4 fv = *(const float4*)&feat[(size_t)nd * FEAT + tx * 4];
        float4 o;
        o.x = acc[i][0] + b3v.x + fv.x;
        o.y = acc[i][1] + b3v.y + fv.y;
        o.z = acc[i][2] + b3v.z + fv.z;
        o.w = acc[i][3] + b3v.w + fv.w;
        if (gi < n) *(float4*)&vtmp[(size_t)gi * FEAT + tx * 4] = o;
    }
}

// ============ Final stage 2: out = relu(vtmp @ weight) ============

__global__ __launch_bounds__(256) void final2_kernel(const float* __restrict__ vtmp,
        const float* __restrict__ weight, float* __restrict__ outc, int n) {
    __shared__ float sWt[FEAT * EMB];   // 32KB
    __shared__ float sV[64 * FEAT];     // 32KB
    int tid = threadIdx.x;
    int base = blockIdx.x * 64;
    for (int i = tid; i < FEAT * EMB; i += 256) sWt[i] = weight[i];
    for (int i = tid; i < 64 * FEAT; i += 256) {
        int r = i >> 7, c = i & 127;
        int gi = base + r;
        sV[i] = (gi < n) ? vtmp[(size_t)gi * FEAT + c] : 0.0f;
    }
    __syncthreads();

    int tx = tid & 15, ty = tid >> 4;
    float acc[4][4];
    #pragma unroll
    for (int i = 0; i < 4; ++i)
        #pragma unroll
        for (int j = 0; j < 4; ++j) acc[i][j] = 0.0f;

    #pragma unroll 4
    for (int k4 = 0; k4 < FEAT / 4; ++k4) {
        float4 a4[4];
        #pragma unroll
        for (int i = 0; i < 4; ++i)
            a4[i] = *(const float4*)&sV[(ty * 4 + i) * FEAT + k4 * 4];
        #pragma unroll
        for (int kk = 0; kk < 4; ++kk) {
            float4 bv = *(const float4*)&sWt[(k4 * 4 + kk) * EMB + tx * 4];
            #pragma unroll
            for (int i = 0; i < 4; ++i) {
                float a = ((const float*)&a4[i])[kk];
                acc[i][0] = fmaf(a, bv.x, acc[i][0]);
                acc[i][1] = fmaf(a, bv.y, acc[i][1]);
                acc[i][2] = fmaf(a, bv.z, acc[i][2]);
                acc[i][3] = fmaf(a, bv.w, acc[i][3]);
            }
        }
    }

    #pragma unroll
    for (int i = 0; i < 4; ++i) {
        int gi = base + ty * 4 + i;
        if (gi < n) {
            float4 o;
            o.x = fmaxf(acc[i][0], 0.0f); o.y = fmaxf(acc[i][1], 0.0f);
            o.z = fmaxf(acc[i][2], 0.0f); o.w = fmaxf(acc[i][3], 0.0f);
            *(float4*)&outc[(size_t)gi * EMB + tx * 4] = o;
        }
    }
}

// ============ launch ============

extern "C" void kernel_launch(void* const* d_in, const int* in_sizes, int n_in,
                              void* d_out, int out_size, void* d_ws, size_t ws_size,
                              hipStream_t stream) {
    const float* feat   = (const float*)d_in[0];
    const float* Wclf   = (const float*)d_in[1];
    const float* bclf   = (const float*)d_in[2];
    const float* W1     = (const float*)d_in[3];
    const float* b1     = (const float*)d_in[4];
    const float* W2     = (const float*)d_in[5];
    const float* b2     = (const float*)d_in[6];
    const float* W3     = (const float*)d_in[7];
    const float* b3     = (const float*)d_in[8];
    const float* weight = (const float*)d_in[9];
    const int* nodes    = (const int*)d_in[10];
    // d_in[11] = r1_neighs: DEAD (AGG_WEIGHT[0] == 0.0)
    const int* edge_src = (const int*)d_in[12];
    const int* edge_dst = (const int*)d_in[13];

    int n       = in_sizes[10];        // 8192
    int n_edges = in_sizes[12];        // 1600000
    int N       = in_sizes[0] / FEAT;  // 50000 (< 65536, required for u16 CSR)

    char* ws = (char*)d_ws;
    size_t off = 0;
    auto alloc = [&](size_t bytes) -> void* {
        void* p = ws + off;
        off = (off + bytes + 255) & ~(size_t)255;
        return p;
    };
    int*   deg    = (int*)  alloc((size_t)N * 4);
    int*   cursor = (int*)  alloc((size_t)N * 4);
    int*   rowptr = (int*)  alloc((size_t)(N + 1) * 4);
    float* dinv   = (float*)alloc((size_t)N * 4);
    int*   bsum   = (int*)  alloc(256 * 4);
    int*   boff   = (int*)  alloc(256 * 4);
    u16*   csr    = (u16*)  alloc((size_t)n_edges * 2);
    float* Axf    = (float*)alloc((size_t)N * EMB * 4);
    u16*   Ayf    = (u16*)  alloc((size_t)N * EMB * 2);
    float* Bxf    = (float*)alloc((size_t)N * EMB * 4);
    u16*   Byf    = (u16*)  alloc((size_t)N * EMB * 2);
    float* hsel   = (float*)alloc((size_t)n * EMB * 4);
    float* vtmp   = (float*)alloc((size_t)n * FEAT * 4);

    float* out_combined = (float*)d_out;                       // [n, 64]
    float* out_scores   = out_combined + (size_t)n * EMB;      // [n, 2]

    hipMemsetAsync(deg, 0, (size_t)N * 4, stream);

    int eb = (n_edges + 255) / 256;
    int sb = (N + 255) / 256;
    count_deg_kernel<<<eb, 256, 0, stream>>>(edge_dst, deg, n_edges);
    block_sum_kernel<<<sb, 256, 0, stream>>>(deg, bsum, N);
    scan_bsum_kernel<<<1, 256, 0, stream>>>(bsum, boff, sb);
    scan_fill_kernel<<<sb, 256, 0, stream>>>(deg, boff, rowptr, dinv, N);
    hipMemcpyAsync(cursor, rowptr, (size_t)N * 4, hipMemcpyDeviceToDevice, stream);
    fill_csr_kernel<<<eb, 256, 0, stream>>>(edge_src, edge_dst, cursor, csr, n_edges);

    int mb = (N + 63) / 64;
    mlp_kernel<<<mb, 256, 0, stream>>>(feat, W1, b1, W2, b2, dinv, Axf, Ayf, N);

    int lb = ((size_t)N * 8 + 255) / 256;
    // conv 0: theta = (3, -3, 0.75)
    lap_kernel<<<lb, 256, 0, stream>>>((const float4*)Axf, (const uint4*)Ayf,
                                       (float4*)Bxf, (uint4*)Byf, rowptr, csr, dinv, N);
    theta_kernel<<<lb, 256, 0, stream>>>((float4*)Axf, (uint4*)Ayf,
                                         (const float4*)Bxf, (const uint4*)Byf,
                                         rowptr, csr, dinv, N, 3.f, -3.f, 0.75f, 0);
    // conv 1: theta = (0, 3, -1.5)
    lap_kernel<<<lb, 256, 0, stream>>>((const float4*)Axf, (const uint4*)Ayf,
                                       (float4*)Bxf, (uint4*)Byf, rowptr, csr, dinv, N);
    theta_kernel<<<lb, 256, 0, stream>>>((float4*)Axf, (uint4*)Ayf,
                                         (const float4*)Bxf, (const uint4*)Byf,
                                         rowptr, csr, dinv, N, 0.f, 3.f, -1.5f, 1);
    // conv 2: theta = (0, 0, 0.75) -> only needed at `nodes`
    lap_kernel<<<lb, 256, 0, stream>>>((const float4*)Axf, (const uint4*)Ayf,
                                       (float4*)Bxf, (uint4*)Byf, rowptr, csr, dinv, N);
    int selb = ((size_t)n * 8 + 255) / 256;
    theta_sel_kernel<<<selb, 256, 0, stream>>>((const float4*)Bxf, (const uint4*)Byf,
                                               rowptr, csr, dinv, nodes,
                                               (float4*)hsel, n, 0.75f);

    int fb = (n + 63) / 64;
    final1_kernel<<<fb, 256, 0, stream>>>(feat, hsel, W3, b3, Wclf, bclf, nodes,
                                          vtmp, out_scores, n);
    final2_kernel<<<fb, 256, 0, stream>>>(vtmp, weight, out_combined, n);
}